// Round 1
// baseline (501.306 us; speedup 1.0000x reference)
//
#include <hip/hip_runtime.h>

// TopKRoute: y = x.reshape(64,-1) @ W^T + b ; top-2 per row; scatter into zeros;
// softmax over all 64 experts.
// B=64 rows, E=64 experts, K=786432. k hardcoded to 2 (setup_inputs fixed).

#define BROWS 64
#define NEXP  64
#define KTOT  786432
#define KB    64          // K per LDS stage
#define SPB   12          // stages per block
#define NBLK  1024        // NBLK * SPB * KB == KTOT

__global__ __launch_bounds__(256) void topk_gemm_partial(
    const float* __restrict__ x, const float* __restrict__ W,
    float* __restrict__ part) {
  // +1 pad: column reads land on stride-65 floats -> 2-way bank alias (free)
  __shared__ float xs[BROWS][KB + 1];
  __shared__ float wsh[NEXP][KB + 1];

  const int t   = threadIdx.x;
  const int blk = blockIdx.x;
  const size_t kbase = (size_t)blk * (KB * SPB);

  // 16x16 thread grid, 4x4 outputs per thread
  const int b0 = (t & 15) * 4;
  const int e0 = (t >> 4) * 4;

  float acc[4][4];
#pragma unroll
  for (int i = 0; i < 4; ++i)
#pragma unroll
    for (int j = 0; j < 4; ++j) acc[i][j] = 0.f;

  // cooperative staging: 64 rows x 16 float4 per matrix = 1024 float4 -> 4/thread
  int rowA[4], colA[4];
#pragma unroll
  for (int l = 0; l < 4; ++l) {
    int idx = l * 256 + t;
    rowA[l] = idx >> 4;          // 0..63
    colA[l] = (idx & 15) * 4;    // 0..60
  }

  float4 rx[4], rw[4];

  auto load_stage = [&](int s) {
#pragma unroll
    for (int l = 0; l < 4; ++l) {
      const size_t off = (size_t)rowA[l] * KTOT + kbase + (size_t)s * KB + colA[l];
      rx[l] = *reinterpret_cast<const float4*>(x + off);
      rw[l] = *reinterpret_cast<const float4*>(W + off);
    }
  };
  auto store_stage = [&]() {
#pragma unroll
    for (int l = 0; l < 4; ++l) {
      xs[rowA[l]][colA[l] + 0] = rx[l].x;
      xs[rowA[l]][colA[l] + 1] = rx[l].y;
      xs[rowA[l]][colA[l] + 2] = rx[l].z;
      xs[rowA[l]][colA[l] + 3] = rx[l].w;
      wsh[rowA[l]][colA[l] + 0] = rw[l].x;
      wsh[rowA[l]][colA[l] + 1] = rw[l].y;
      wsh[rowA[l]][colA[l] + 2] = rw[l].z;
      wsh[rowA[l]][colA[l] + 3] = rw[l].w;
    }
  };

  load_stage(0);
  store_stage();
  __syncthreads();

  for (int s = 0; s < SPB; ++s) {
    const bool more = (s + 1 < SPB);
    if (more) load_stage(s + 1);   // issue next-stage global loads before compute

#pragma unroll 8
    for (int kk = 0; kk < KB; ++kk) {
      float a[4], w[4];
#pragma unroll
      for (int i = 0; i < 4; ++i) a[i] = xs[b0 + i][kk];
#pragma unroll
      for (int j = 0; j < 4; ++j) w[j] = wsh[e0 + j][kk];
#pragma unroll
      for (int i = 0; i < 4; ++i)
#pragma unroll
        for (int j = 0; j < 4; ++j) acc[i][j] = fmaf(a[i], w[j], acc[i][j]);
    }

    __syncthreads();
    if (more) store_stage();
    __syncthreads();
  }

  // one 64x64 partial per block
  float* p = part + (size_t)blk * (BROWS * NEXP);
#pragma unroll
  for (int i = 0; i < 4; ++i)
#pragma unroll
    for (int j = 0; j < 4; ++j)
      p[(b0 + i) * NEXP + (e0 + j)] = acc[i][j];
}

__global__ __launch_bounds__(256) void topk_reduce(
    const float* __restrict__ part, const float* __restrict__ bias,
    float* __restrict__ out) {
  const int b = blockIdx.x;   // row 0..63
  const int t = threadIdx.x;
  const int e = t & 63;
  const int g = t >> 6;       // 4 partial-groups

  float s = 0.f;
  for (int p = g; p < NBLK; p += 4)
    s += part[(size_t)p * (BROWS * NEXP) + b * NEXP + e];

  __shared__ float red[4][64];
  red[g][e] = s;
  __syncthreads();

  if (t < 64) {
    float y = red[0][e] + red[1][e] + red[2][e] + red[3][e] + bias[e];

    // wave-wide (64-lane) argmax, lowest index wins ties (matches lax.top_k)
    float v1 = y; int i1 = e;
#pragma unroll
    for (int off = 32; off > 0; off >>= 1) {
      float ov = __shfl_xor(v1, off);
      int   oi = __shfl_xor(i1, off);
      if (ov > v1 || (ov == v1 && oi < i1)) { v1 = ov; i1 = oi; }
    }
    float ym = (e == i1) ? -3.4e38f : y;
    float v2 = ym; int i2 = e;
#pragma unroll
    for (int off = 32; off > 0; off >>= 1) {
      float ov = __shfl_xor(v2, off);
      int   oi = __shfl_xor(i2, off);
      if (ov > v2 || (ov == v2 && oi < i2)) { v2 = ov; i2 = oi; }
    }

    // softmax over mask: zeros everywhere except top-2 keep their logits
    const float M = fmaxf(v1, 0.f);
    const float z = 62.f * __expf(0.f - M) + __expf(v1 - M) + __expf(v2 - M);
    const float m_e = (e == i1) ? v1 : ((e == i2) ? v2 : 0.f);
    out[b * NEXP + e] = __expf(m_e - M) / z;
  }
}

extern "C" void kernel_launch(void* const* d_in, const int* in_sizes, int n_in,
                              void* d_out, int out_size, void* d_ws, size_t ws_size,
                              hipStream_t stream) {
  const float* x    = (const float*)d_in[0];
  const float* W    = (const float*)d_in[1];
  const float* bias = (const float*)d_in[2];
  // d_in[3] is k (always 2 for this problem; hardcoded in topk_reduce)
  float* part = (float*)d_ws;          // NBLK * 4096 * 4B = 16 MB
  float* out  = (float*)d_out;

  topk_gemm_partial<<<NBLK, 256, 0, stream>>>(x, W, part);
  topk_reduce<<<64, 256, 0, stream>>>(part, bias, out);
}